// Round 1
// baseline (1470.658 us; speedup 1.0000x reference)
//
#include <hip/hip_runtime.h>
#include <hip/hip_bf16.h>
#include <stdint.h>

#define N_DIM 8192
#define H_DIM 1024
#define E_DIM 8192
#define PENALTY_F 10.0f

typedef unsigned short u16;
typedef unsigned int u32;
typedef __attribute__((ext_vector_type(8))) short bf16x8;
typedef __attribute__((ext_vector_type(4))) float f32x4;

__device__ __forceinline__ u16 f2bf(float f) {
  u32 u = __float_as_uint(f);
  u = (u + 0x7fffu + ((u >> 16) & 1u)) >> 16;
  return (u16)u;
}
__device__ __forceinline__ float bf2f(u16 h) {
  return __uint_as_float(((u32)h) << 16);
}

// async global->LDS, 16B per lane, LDS dest = wave-uniform base + lane*16
#define GLD16(ldsptr, gptr)                                                     \
  __builtin_amdgcn_global_load_lds(                                             \
      (__attribute__((address_space(1))) void*)(gptr),                          \
      (__attribute__((address_space(3))) void*)(ldsptr), 16, 0, 0)

// ---------------------------------------------------------------------------
// Gather rows of A (fp32) into stacked bf16 X: rows [0,E) = A[ni], [E,2E) = A[nj]
// ---------------------------------------------------------------------------
__global__ void gather_convert(const float* __restrict__ A,
                               const int* __restrict__ edges,
                               u16* __restrict__ Xb) {
  int r = blockIdx.x;  // 0..2E-1
  int e = (r < E_DIM) ? r : (r - E_DIM);
  int which = (r < E_DIM) ? 0 : 1;
  int src = edges[e * 2 + which];
  const float4* arow = (const float4*)(A + (size_t)src * N_DIM);
  ushort4* drow = (ushort4*)(Xb + (size_t)r * N_DIM);
  for (int i = threadIdx.x; i < N_DIM / 4; i += blockDim.x) {
    float4 v = arow[i];
    ushort4 o;
    o.x = f2bf(v.x); o.y = f2bf(v.y); o.z = f2bf(v.z); o.w = f2bf(v.w);
    drow[i] = o;
  }
}

// ---------------------------------------------------------------------------
// Elementwise fp32 -> bf16 (for W1, W2)
// ---------------------------------------------------------------------------
__global__ void convert_f32_bf16(const float* __restrict__ in,
                                 u16* __restrict__ out, int n4) {
  int i = blockIdx.x * blockDim.x + threadIdx.x;
  if (i < n4) {
    float4 v = ((const float4*)in)[i];
    ushort4 o;
    o.x = f2bf(v.x); o.y = f2bf(v.y); o.z = f2bf(v.z); o.w = f2bf(v.w);
    ((ushort4*)out)[i] = o;
  }
}

// ---------------------------------------------------------------------------
// block reduce helpers (blockDim.x == 256)
// ---------------------------------------------------------------------------
__device__ __forceinline__ float block_reduce1(float v) {
  __shared__ float buf[4];
  for (int o = 32; o; o >>= 1) v += __shfl_down(v, o, 64);
  int lane = threadIdx.x & 63, w = threadIdx.x >> 6;
  if (lane == 0) buf[w] = v;
  __syncthreads();
  float r = 0.f;
  if (threadIdx.x == 0) r = buf[0] + buf[1] + buf[2] + buf[3];
  return r;  // valid on thread 0
}

__device__ __forceinline__ void block_reduce3(float& a, float& b, float& c) {
  __shared__ float buf[3][4];
  for (int o = 32; o; o >>= 1) {
    a += __shfl_down(a, o, 64);
    b += __shfl_down(b, o, 64);
    c += __shfl_down(c, o, 64);
  }
  int lane = threadIdx.x & 63, w = threadIdx.x >> 6;
  if (lane == 0) { buf[0][w] = a; buf[1][w] = b; buf[2][w] = c; }
  __syncthreads();
  if (threadIdx.x == 0) {
    a = buf[0][0] + buf[0][1] + buf[0][2] + buf[0][3];
    b = buf[1][0] + buf[1][1] + buf[1][2] + buf[1][3];
    c = buf[2][0] + buf[2][1] + buf[2][2] + buf[2][3];
  }
}

// ---------------------------------------------------------------------------
// loss_r piece: atomicAdd(out, ||row||_2 * scale) for each row (1 block/row)
// ---------------------------------------------------------------------------
__global__ void rownorm_scaled(const float* __restrict__ M, int cols,
                               float scale, float* __restrict__ out) {
  const float4* row = (const float4*)(M + (size_t)blockIdx.x * cols);
  float s = 0.f;
  for (int i = threadIdx.x; i < cols / 4; i += blockDim.x) {
    float4 v = row[i];
    s += v.x * v.x + v.y * v.y + v.z * v.z + v.w * v.w;
  }
  s = block_reduce1(s);
  if (threadIdx.x == 0) atomicAdd(out, sqrtf(s) * scale);
}

// ---------------------------------------------------------------------------
// GEMM: C[M][Nd] = sigmoid( X[M][K] * W[Nd][K]^T + bias ), all bf16 in/out,
// fp32 MFMA accumulate. 128x128 tile, BK=64, 256 thr = 4 waves (2x2), each
// wave 64x64 via 4x4 MFMA 16x16x32 tiles. global_load_lds(16B) staging with
// XOR chunk swizzle (chunk^row&7) so ds_read_b128 frag reads are 2-way max.
// ---------------------------------------------------------------------------
#define BM 128
#define BN 128
#define BK 64

__global__ __launch_bounds__(256) void gemm_bt_sigmoid(
    const u16* __restrict__ Xg,   // [M][K]
    const u16* __restrict__ Wg,   // [Nd][K]
    const float* __restrict__ bias,  // [Nd]
    u16* __restrict__ Cg,         // [M][Nd]
    int K, int Nd) {
  __shared__ __align__(16) u16 Xs[BM * BK];
  __shared__ __align__(16) u16 Ws[BN * BK];

  const int tid = threadIdx.x;
  const int wave = tid >> 6, lane = tid & 63;
  const int wr = wave >> 1, wc = wave & 1;
  const size_t rowBase = (size_t)blockIdx.y * BM;
  const size_t colBase = (size_t)blockIdx.x * BN;

  f32x4 acc[4][4] = {};

  const int i8 = lane >> 3;        // row within an 8-row load
  const int c8 = lane & 7;         // LDS slot chunk
  const int sw = c8 ^ i8;          // swizzled global chunk index

  for (int k0 = 0; k0 < K; k0 += BK) {
#pragma unroll
    for (int j = 0; j < 4; ++j) {
      const int r0 = (wave * 4 + j) * 8;
      const u16* gx = Xg + (rowBase + r0 + i8) * (size_t)K + (k0 + sw * 8);
      GLD16(&Xs[r0 * 64], gx);
      const u16* gw = Wg + (colBase + r0 + i8) * (size_t)K + (k0 + sw * 8);
      GLD16(&Ws[r0 * 64], gw);
    }
    __syncthreads();

    const int quad = lane >> 4;
    const int m15 = lane & 15;
#pragma unroll
    for (int kk = 0; kk < 2; ++kk) {
      const int q0 = kk * 4 + quad;  // global k-chunk for this quad
      bf16x8 af[4], bfr[4];
#pragma unroll
      for (int t = 0; t < 4; ++t) {
        const int m = wr * 64 + t * 16 + m15;
        af[t] = *(const bf16x8*)&Xs[m * 64 + (q0 ^ (m & 7)) * 8];
        const int n = wc * 64 + t * 16 + m15;
        bfr[t] = *(const bf16x8*)&Ws[n * 64 + (q0 ^ (n & 7)) * 8];
      }
#pragma unroll
      for (int mt = 0; mt < 4; ++mt)
#pragma unroll
        for (int nt = 0; nt < 4; ++nt)
          acc[mt][nt] = __builtin_amdgcn_mfma_f32_16x16x32_bf16(
              af[mt], bfr[nt], acc[mt][nt], 0, 0, 0);
    }
    __syncthreads();
  }

  // epilogue: bias + sigmoid + bf16 store
  const int m15 = lane & 15, quad = lane >> 4;
  float bv[4];
#pragma unroll
  for (int nt = 0; nt < 4; ++nt)
    bv[nt] = bias[colBase + wc * 64 + nt * 16 + m15];
#pragma unroll
  for (int mt = 0; mt < 4; ++mt) {
#pragma unroll
    for (int i = 0; i < 4; ++i) {
      const size_t grow = rowBase + wr * 64 + mt * 16 + quad * 4 + i;
      u16* crow = Cg + grow * (size_t)Nd + colBase + wc * 64 + m15;
#pragma unroll
      for (int nt = 0; nt < 4; ++nt) {
        float x = acc[mt][nt][i] + bv[nt];
        float s = 1.0f / (1.0f + __expf(-x));
        crow[nt * 16] = f2bf(s);
      }
    }
  }
}

// ---------------------------------------------------------------------------
// loss_1 layer-1: per edge, ||H1[e]-H1[E+e]||_2 * lab[e]  (H = 1024 cols)
// ---------------------------------------------------------------------------
__global__ void edge_loss_h(const u16* __restrict__ H1,
                            const int* __restrict__ labels,
                            float* __restrict__ out) {
  int e = blockIdx.x;
  const ushort4* hi = (const ushort4*)(H1 + (size_t)e * H_DIM);
  const ushort4* hj = (const ushort4*)(H1 + (size_t)(e + E_DIM) * H_DIM);
  float s = 0.f;
  for (int i = threadIdx.x; i < H_DIM / 4; i += blockDim.x) {
    ushort4 a = hi[i], b = hj[i];
    float d0 = bf2f(a.x) - bf2f(b.x);
    float d1 = bf2f(a.y) - bf2f(b.y);
    float d2 = bf2f(a.z) - bf2f(b.z);
    float d3 = bf2f(a.w) - bf2f(b.w);
    s += d0 * d0 + d1 * d1 + d2 * d2 + d3 * d3;
  }
  s = block_reduce1(s);
  if (threadIdx.x == 0 && labels[e] != 0) atomicAdd(out, sqrtf(s));
}

// ---------------------------------------------------------------------------
// loss_1 layer-2 + loss_2: per edge,
//   lab*||Hi2-Hj2|| + factor*(||Xi-Hi2|| + ||Xj-Hj2||)   (N = 8192 cols)
// ---------------------------------------------------------------------------
__global__ void edge_loss_final(const u16* __restrict__ H2,
                                const u16* __restrict__ Xb,
                                const int* __restrict__ labels,
                                float* __restrict__ out) {
  int e = blockIdx.x;
  const ushort4* hi = (const ushort4*)(H2 + (size_t)e * N_DIM);
  const ushort4* hj = (const ushort4*)(H2 + (size_t)(e + E_DIM) * N_DIM);
  const ushort4* xi = (const ushort4*)(Xb + (size_t)e * N_DIM);
  const ushort4* xj = (const ushort4*)(Xb + (size_t)(e + E_DIM) * N_DIM);
  float s12 = 0.f, si = 0.f, sj = 0.f;
  for (int i = threadIdx.x; i < N_DIM / 4; i += blockDim.x) {
    ushort4 a = hi[i], b = hj[i], x = xi[i], y = xj[i];
    float ha0 = bf2f(a.x), ha1 = bf2f(a.y), ha2 = bf2f(a.z), ha3 = bf2f(a.w);
    float hb0 = bf2f(b.x), hb1 = bf2f(b.y), hb2 = bf2f(b.z), hb3 = bf2f(b.w);
    float d;
    d = ha0 - hb0; s12 += d * d; d = ha1 - hb1; s12 += d * d;
    d = ha2 - hb2; s12 += d * d; d = ha3 - hb3; s12 += d * d;
    d = bf2f(x.x) - ha0; si += d * d; d = bf2f(x.y) - ha1; si += d * d;
    d = bf2f(x.z) - ha2; si += d * d; d = bf2f(x.w) - ha3; si += d * d;
    d = bf2f(y.x) - hb0; sj += d * d; d = bf2f(y.y) - hb1; sj += d * d;
    d = bf2f(y.z) - hb2; sj += d * d; d = bf2f(y.w) - hb3; sj += d * d;
  }
  block_reduce3(s12, si, sj);
  if (threadIdx.x == 0) {
    float lab = (labels[e] != 0) ? 1.f : 0.f;
    float fac = (labels[e] != 0) ? PENALTY_F : 1.f;
    atomicAdd(out, lab * sqrtf(s12) + fac * (sqrtf(si) + sqrtf(sj)));
  }
}

// ---------------------------------------------------------------------------
extern "C" void kernel_launch(void* const* d_in, const int* in_sizes, int n_in,
                              void* d_out, int out_size, void* d_ws,
                              size_t ws_size, hipStream_t stream) {
  const float* A = (const float*)d_in[0];
  const float* W1 = (const float*)d_in[1];
  const float* b1 = (const float*)d_in[2];
  const float* W2 = (const float*)d_in[3];
  const float* b2 = (const float*)d_in[4];
  const int* edges = (const int*)d_in[5];
  const int* labels = (const int*)d_in[6];
  float* out = (float*)d_out;

  // workspace layout (bytes)
  char* ws = (char*)d_ws;
  u16* Xb  = (u16*)(ws);                       // 2E x N bf16   (256 MB)
  u16* H1  = (u16*)(ws + 268435456ull);        // 2E x H bf16   ( 32 MB)
  u16* H2  = (u16*)(ws + 301989888ull);        // 2E x N bf16   (256 MB)
  u16* W1b = (u16*)(ws + 570425344ull);        // H x N bf16    ( 16 MB)
  u16* W2b = (u16*)(ws + 587202560ull);        // N x H bf16    ( 16 MB)

  hipMemsetAsync(out, 0, sizeof(float), stream);

  // gather + casts
  gather_convert<<<2 * E_DIM, 256, 0, stream>>>(A, edges, Xb);
  convert_f32_bf16<<<(H_DIM * N_DIM / 4 + 255) / 256, 256, 0, stream>>>(
      W1, W1b, H_DIM * N_DIM / 4);
  convert_f32_bf16<<<(N_DIM * H_DIM / 4 + 255) / 256, 256, 0, stream>>>(
      W2, W2b, N_DIM * H_DIM / 4);

  // loss_r (exact, fp32): E * (sum row norms W1 + ||b1|| + sum row norms W2 + ||b2||)
  rownorm_scaled<<<H_DIM, 256, 0, stream>>>(W1, N_DIM, (float)E_DIM, out);
  rownorm_scaled<<<N_DIM, 256, 0, stream>>>(W2, H_DIM, (float)E_DIM, out);
  rownorm_scaled<<<1, 256, 0, stream>>>(b1, H_DIM, (float)E_DIM, out);
  rownorm_scaled<<<1, 256, 0, stream>>>(b2, N_DIM, (float)E_DIM, out);

  // layer 1: H1 = sigmoid(X @ W1^T + b1)   [2E x H]
  gemm_bt_sigmoid<<<dim3(H_DIM / BN, 2 * E_DIM / BM), 256, 0, stream>>>(
      Xb, W1b, b1, H1, N_DIM, H_DIM);
  edge_loss_h<<<E_DIM, 256, 0, stream>>>(H1, labels, out);

  // layer 2: H2 = sigmoid(H1 @ W2^T + b2)  [2E x N]
  gemm_bt_sigmoid<<<dim3(N_DIM / BN, 2 * E_DIM / BM), 256, 0, stream>>>(
      H1, W2b, b2, H2, H_DIM, N_DIM);
  edge_loss_final<<<E_DIM, 256, 0, stream>>>(H2, Xb, labels, out);
}

// Round 2
// 1263.981 us; speedup vs baseline: 1.1635x; 1.1635x over previous
//
#include <hip/hip_runtime.h>
#include <hip/hip_bf16.h>
#include <stdint.h>

#define N_DIM 8192
#define H_DIM 1024
#define E_DIM 8192
#define PENALTY_F 10.0f
#define WSCALE 16.0f      // weights and H outputs stored *16 in e4m3
#define INV_WSCALE 0.0625f

typedef unsigned short u16;
typedef unsigned char u8;
typedef unsigned int u32;
typedef __attribute__((ext_vector_type(4))) float f32x4;
typedef __attribute__((ext_vector_type(2))) float f32x2;
typedef __attribute__((ext_vector_type(2))) long i64x2;

__device__ __forceinline__ u16 f2bf(float f) {
  u32 u = __float_as_uint(f);
  u = (u + 0x7fffu + ((u >> 16) & 1u)) >> 16;
  return (u16)u;
}
__device__ __forceinline__ float bf2f(u16 h) {
  return __uint_as_float(((u32)h) << 16);
}
// pack 4 floats -> 4 e4m3 bytes (OCP on gfx950)
__device__ __forceinline__ u32 pack4_fp8(float a, float b, float c, float d) {
  u32 p = __builtin_amdgcn_cvt_pk_fp8_f32(a, b, 0, false);
  p = __builtin_amdgcn_cvt_pk_fp8_f32(c, d, p, true);
  return p;
}
__device__ __forceinline__ u8 f2fp8(float a) {
  return (u8)(__builtin_amdgcn_cvt_pk_fp8_f32(a, a, 0, false) & 0xFF);
}
__device__ __forceinline__ f32x2 unpk_lo(u32 v) {
  return __builtin_amdgcn_cvt_pk_f32_fp8(v, false);
}
__device__ __forceinline__ f32x2 unpk_hi(u32 v) {
  return __builtin_amdgcn_cvt_pk_f32_fp8(v, true);
}

#define GLD16(ldsptr, gptr)                                                     \
  __builtin_amdgcn_global_load_lds(                                             \
      (__attribute__((address_space(1))) void*)(gptr),                          \
      (__attribute__((address_space(3))) void*)(ldsptr), 16, 0, 0)

// ---------------------------------------------------------------------------
// Gather rows of A into bf16 Xb (for exact-ish loss_2) and fp8 X8 (for GEMM1)
// ---------------------------------------------------------------------------
__global__ void gather_convert(const float* __restrict__ A,
                               const int* __restrict__ edges,
                               u16* __restrict__ Xb, u8* __restrict__ X8) {
  int r = blockIdx.x;  // 0..2E-1
  int e = (r < E_DIM) ? r : (r - E_DIM);
  int which = (r < E_DIM) ? 0 : 1;
  int src = edges[e * 2 + which];
  const float4* arow = (const float4*)(A + (size_t)src * N_DIM);
  ushort4* drow = (ushort4*)(Xb + (size_t)r * N_DIM);
  u32* frow = (u32*)(X8 + (size_t)r * N_DIM);
  for (int i = threadIdx.x; i < N_DIM / 4; i += blockDim.x) {
    float4 v = arow[i];
    ushort4 o;
    o.x = f2bf(v.x); o.y = f2bf(v.y); o.z = f2bf(v.z); o.w = f2bf(v.w);
    drow[i] = o;
    frow[i] = pack4_fp8(v.x, v.y, v.z, v.w);
  }
}

// fp32 -> fp8 with scale (for W1, W2)
__global__ void convert_f32_fp8(const float* __restrict__ in,
                                u8* __restrict__ out, int n4, float scale) {
  int i = blockIdx.x * blockDim.x + threadIdx.x;
  if (i < n4) {
    float4 v = ((const float4*)in)[i];
    ((u32*)out)[i] =
        pack4_fp8(v.x * scale, v.y * scale, v.z * scale, v.w * scale);
  }
}

// ---------------------------------------------------------------------------
// block reduce helpers (blockDim.x == 256)
// ---------------------------------------------------------------------------
__device__ __forceinline__ float block_reduce1(float v) {
  __shared__ float buf[4];
  for (int o = 32; o; o >>= 1) v += __shfl_down(v, o, 64);
  int lane = threadIdx.x & 63, w = threadIdx.x >> 6;
  if (lane == 0) buf[w] = v;
  __syncthreads();
  float r = 0.f;
  if (threadIdx.x == 0) r = buf[0] + buf[1] + buf[2] + buf[3];
  return r;  // valid on thread 0
}

__device__ __forceinline__ void block_reduce3(float& a, float& b, float& c) {
  __shared__ float buf[3][4];
  for (int o = 32; o; o >>= 1) {
    a += __shfl_down(a, o, 64);
    b += __shfl_down(b, o, 64);
    c += __shfl_down(c, o, 64);
  }
  int lane = threadIdx.x & 63, w = threadIdx.x >> 6;
  if (lane == 0) { buf[0][w] = a; buf[1][w] = b; buf[2][w] = c; }
  __syncthreads();
  if (threadIdx.x == 0) {
    a = buf[0][0] + buf[0][1] + buf[0][2] + buf[0][3];
    b = buf[1][0] + buf[1][1] + buf[1][2] + buf[1][3];
    c = buf[2][0] + buf[2][1] + buf[2][2] + buf[2][3];
  }
}

// ---------------------------------------------------------------------------
// loss_r piece (exact fp32): atomicAdd(out, ||row|| * scale), 1 block/row
// ---------------------------------------------------------------------------
__global__ void rownorm_scaled(const float* __restrict__ M, int cols,
                               float scale, float* __restrict__ out) {
  const float4* row = (const float4*)(M + (size_t)blockIdx.x * cols);
  float s = 0.f;
  for (int i = threadIdx.x; i < cols / 4; i += blockDim.x) {
    float4 v = row[i];
    s += v.x * v.x + v.y * v.y + v.z * v.z + v.w * v.w;
  }
  s = block_reduce1(s);
  if (threadIdx.x == 0) atomicAdd(out, sqrtf(s) * scale);
}

// ---------------------------------------------------------------------------
// fp8 GEMM: C = fp8( WSCALE * sigmoid( invScale * (A B^T) + bias ) )
// A[M][K], B[Nd][K] both e4m3, row-major, K multiple of 128.
// 128x128 tile, 128 fp8 per K-iter (= 128 B/row, byte-identical staging to the
// bf16 kernel), 4 waves 2x2, each 64x64 via 4x4 MFMA 16x16x32_fp8 tiles.
// Each 16-B XOR-swizzled LDS unit feeds two MFMA k-steps (low/high 8 B);
// the global-k permutation is identical for A and B so the product is exact.
// ---------------------------------------------------------------------------
#define BM 128
#define BN 128
#define BKB 128  // K-bytes (=elements) per tile iteration

__global__ __launch_bounds__(256) void gemm_fp8_sigmoid(
    const u8* __restrict__ Ag,    // [M][K]
    const u8* __restrict__ Bg,    // [Nd][K]
    const float* __restrict__ bias,
    u8* __restrict__ Cg,          // [M][Nd] e4m3, value*WSCALE
    float invScale, int K, int Nd) {
  __shared__ __align__(16) u8 Xs[BM * BKB];
  __shared__ __align__(16) u8 Ws[BN * BKB];

  const int tid = threadIdx.x;
  const int wave = tid >> 6, lane = tid & 63;
  const int wr = wave >> 1, wc = wave & 1;
  const size_t rowBase = (size_t)blockIdx.y * BM;
  const size_t colBase = (size_t)blockIdx.x * BN;

  f32x4 acc[4][4] = {};

  const int i8 = lane >> 3;  // row within 8-row group
  const int c8 = lane & 7;   // LDS 16-B slot
  const int sw = c8 ^ i8;    // swizzled global 16-B unit

  for (int k0 = 0; k0 < K; k0 += BKB) {
#pragma unroll
    for (int j = 0; j < 4; ++j) {
      const int r0 = (wave * 4 + j) * 8;
      const u8* gx = Ag + (rowBase + r0 + i8) * (size_t)K + (k0 + sw * 16);
      GLD16(&Xs[r0 * BKB], gx);
      const u8* gw = Bg + (colBase + r0 + i8) * (size_t)K + (k0 + sw * 16);
      GLD16(&Ws[r0 * BKB], gw);
    }
    __syncthreads();

    const int quad = lane >> 4;
    const int m15 = lane & 15;
#pragma unroll
    for (int kk = 0; kk < 2; ++kk) {
      const int q0 = kk * 4 + quad;  // 16-B unit index for this quad
      i64x2 af[4], bfr[4];
#pragma unroll
      for (int t = 0; t < 4; ++t) {
        const int m = wr * 64 + t * 16 + m15;
        af[t] = *(const i64x2*)&Xs[m * BKB + (q0 ^ (m & 7)) * 16];
        const int n = wc * 64 + t * 16 + m15;
        bfr[t] = *(const i64x2*)&Ws[n * BKB + (q0 ^ (n & 7)) * 16];
      }
#pragma unroll
      for (int mt = 0; mt < 4; ++mt)
#pragma unroll
        for (int nt = 0; nt < 4; ++nt) {
          acc[mt][nt] = __builtin_amdgcn_mfma_f32_16x16x32_fp8_fp8(
              af[mt].x, bfr[nt].x, acc[mt][nt], 0, 0, 0);
          acc[mt][nt] = __builtin_amdgcn_mfma_f32_16x16x32_fp8_fp8(
              af[mt].y, bfr[nt].y, acc[mt][nt], 0, 0, 0);
        }
    }
    __syncthreads();
  }

  // epilogue: scale + bias + sigmoid, store fp8 (value * WSCALE)
  const int m15 = lane & 15, quad = lane >> 4;
  float bv[4];
#pragma unroll
  for (int nt = 0; nt < 4; ++nt)
    bv[nt] = bias[colBase + wc * 64 + nt * 16 + m15];
#pragma unroll
  for (int mt = 0; mt < 4; ++mt) {
#pragma unroll
    for (int i = 0; i < 4; ++i) {
      const size_t grow = rowBase + wr * 64 + mt * 16 + quad * 4 + i;
      u8* crow = Cg + grow * (size_t)Nd + colBase + wc * 64 + m15;
#pragma unroll
      for (int nt = 0; nt < 4; ++nt) {
        float x = acc[mt][nt][i] * invScale + bv[nt];
        float s = 1.0f / (1.0f + __expf(-x));
        crow[nt * 16] = f2fp8(s * WSCALE);
      }
    }
  }
}

// ---------------------------------------------------------------------------
// loss_1 layer-1: per edge, ||H1[e]-H1[E+e]|| * lab ; H1 is e4m3 *WSCALE
// ---------------------------------------------------------------------------
__global__ void edge_loss_h(const u8* __restrict__ H1,
                            const int* __restrict__ labels,
                            float* __restrict__ out) {
  int e = blockIdx.x;
  const u32* hi = (const u32*)(H1 + (size_t)e * H_DIM);
  const u32* hj = (const u32*)(H1 + (size_t)(e + E_DIM) * H_DIM);
  float s = 0.f;
  for (int i = threadIdx.x; i < H_DIM / 4; i += blockDim.x) {
    u32 a = hi[i], b = hj[i];
    f32x2 al = unpk_lo(a), ah = unpk_hi(a);
    f32x2 bl = unpk_lo(b), bh = unpk_hi(b);
    float d0 = al.x - bl.x, d1 = al.y - bl.y;
    float d2 = ah.x - bh.x, d3 = ah.y - bh.y;
    s += d0 * d0 + d1 * d1 + d2 * d2 + d3 * d3;
  }
  s = block_reduce1(s);
  // both rows scaled *WSCALE -> norm scaled *WSCALE
  if (threadIdx.x == 0 && labels[e] != 0)
    atomicAdd(out, sqrtf(s) * INV_WSCALE);
}

// ---------------------------------------------------------------------------
// loss_1 layer-2 + loss_2; H2 is e4m3 *WSCALE, Xb is bf16 unscaled
// ---------------------------------------------------------------------------
__global__ void edge_loss_final(const u8* __restrict__ H2,
                                const u16* __restrict__ Xb,
                                const int* __restrict__ labels,
                                float* __restrict__ out) {
  int e = blockIdx.x;
  const u32* hi = (const u32*)(H2 + (size_t)e * N_DIM);
  const u32* hj = (const u32*)(H2 + (size_t)(e + E_DIM) * N_DIM);
  const ushort4* xi = (const ushort4*)(Xb + (size_t)e * N_DIM);
  const ushort4* xj = (const ushort4*)(Xb + (size_t)(e + E_DIM) * N_DIM);
  float s12 = 0.f, si = 0.f, sj = 0.f;
  for (int i = threadIdx.x; i < N_DIM / 4; i += blockDim.x) {
    u32 a = hi[i], b = hj[i];
    ushort4 x = xi[i], y = xj[i];
    f32x2 al = unpk_lo(a), ah = unpk_hi(a);
    f32x2 bl = unpk_lo(b), bh = unpk_hi(b);
    float ha0 = al.x, ha1 = al.y, ha2 = ah.x, ha3 = ah.y;  // 16*Hi
    float hb0 = bl.x, hb1 = bl.y, hb2 = bh.x, hb3 = bh.y;  // 16*Hj
    float d;
    d = ha0 - hb0; s12 += d * d; d = ha1 - hb1; s12 += d * d;
    d = ha2 - hb2; s12 += d * d; d = ha3 - hb3; s12 += d * d;
    // 16*Xi - 16*Hi
    d = WSCALE * bf2f(x.x) - ha0; si += d * d;
    d = WSCALE * bf2f(x.y) - ha1; si += d * d;
    d = WSCALE * bf2f(x.z) - ha2; si += d * d;
    d = WSCALE * bf2f(x.w) - ha3; si += d * d;
    d = WSCALE * bf2f(y.x) - hb0; sj += d * d;
    d = WSCALE * bf2f(y.y) - hb1; sj += d * d;
    d = WSCALE * bf2f(y.z) - hb2; sj += d * d;
    d = WSCALE * bf2f(y.w) - hb3; sj += d * d;
  }
  block_reduce3(s12, si, sj);
  if (threadIdx.x == 0) {
    float lab = (labels[e] != 0) ? 1.f : 0.f;
    float fac = (labels[e] != 0) ? PENALTY_F : 1.f;
    atomicAdd(out, (lab * sqrtf(s12) + fac * (sqrtf(si) + sqrtf(sj))) *
                       INV_WSCALE);
  }
}

// ---------------------------------------------------------------------------
extern "C" void kernel_launch(void* const* d_in, const int* in_sizes, int n_in,
                              void* d_out, int out_size, void* d_ws,
                              size_t ws_size, hipStream_t stream) {
  const float* A = (const float*)d_in[0];
  const float* W1 = (const float*)d_in[1];
  const float* b1 = (const float*)d_in[2];
  const float* W2 = (const float*)d_in[3];
  const float* b2 = (const float*)d_in[4];
  const int* edges = (const int*)d_in[5];
  const int* labels = (const int*)d_in[6];
  float* out = (float*)d_out;

  // workspace layout (bytes), total 544 MB
  char* ws = (char*)d_ws;
  u16* Xb  = (u16*)(ws);                      // 2E x N bf16   256 MB
  u8* X8   = (u8*)(ws + 268435456ull);        // 2E x N fp8    128 MB
  u8* H1_8 = (u8*)(ws + 402653184ull);        // 2E x H fp8     16 MB
  u8* H2_8 = (u8*)(ws + 419430400ull);        // 2E x N fp8    128 MB
  u8* W1_8 = (u8*)(ws + 553648128ull);        // H x N fp8       8 MB
  u8* W2_8 = (u8*)(ws + 562036736ull);        // N x H fp8       8 MB

  hipMemsetAsync(out, 0, sizeof(float), stream);

  gather_convert<<<2 * E_DIM, 256, 0, stream>>>(A, edges, Xb, X8);
  convert_f32_fp8<<<(H_DIM * N_DIM / 4 + 255) / 256, 256, 0, stream>>>(
      W1, W1_8, H_DIM * N_DIM / 4, WSCALE);
  convert_f32_fp8<<<(N_DIM * H_DIM / 4 + 255) / 256, 256, 0, stream>>>(
      W2, W2_8, N_DIM * H_DIM / 4, WSCALE);

  // loss_r exact in fp32
  rownorm_scaled<<<H_DIM, 256, 0, stream>>>(W1, N_DIM, (float)E_DIM, out);
  rownorm_scaled<<<N_DIM, 256, 0, stream>>>(W2, H_DIM, (float)E_DIM, out);
  rownorm_scaled<<<1, 256, 0, stream>>>(b1, H_DIM, (float)E_DIM, out);
  rownorm_scaled<<<1, 256, 0, stream>>>(b2, N_DIM, (float)E_DIM, out);

  // layer 1: H1 = sigmoid(X @ W1^T + b1)  [2E x H], fp8 path, W scaled *16
  gemm_fp8_sigmoid<<<dim3(H_DIM / BN, 2 * E_DIM / BM), 256, 0, stream>>>(
      X8, W1_8, b1, H1_8, INV_WSCALE, N_DIM, H_DIM);
  edge_loss_h<<<E_DIM, 256, 0, stream>>>(H1_8, labels, out);

  // layer 2: H2 = sigmoid(H1 @ W2^T + b2) [2E x N]; A*16 and B*16 -> /256
  gemm_fp8_sigmoid<<<dim3(N_DIM / BN, 2 * E_DIM / BM), 256, 0, stream>>>(
      H1_8, W2_8, b2, H2_8, INV_WSCALE * INV_WSCALE, H_DIM, N_DIM);
  edge_loss_final<<<E_DIM, 256, 0, stream>>>(H2_8, Xb, labels, out);
}

// Round 3
// 890.846 us; speedup vs baseline: 1.6509x; 1.4189x over previous
//
#include <hip/hip_runtime.h>
#include <hip/hip_bf16.h>
#include <stdint.h>

#define N_DIM 8192
#define H_DIM 1024
#define E_DIM 8192
#define PENALTY_F 10.0f
#define WSCALE 16.0f      // weights and H outputs stored *16 in e4m3
#define INV_WSCALE 0.0625f

typedef unsigned short u16;
typedef unsigned char u8;
typedef unsigned int u32;
typedef __attribute__((ext_vector_type(4))) float f32x4;
typedef __attribute__((ext_vector_type(2))) float f32x2;
typedef __attribute__((ext_vector_type(4))) int i32x4;
typedef __attribute__((ext_vector_type(8))) int i32x8;

// pack 4 floats -> 4 e4m3 bytes (OCP on gfx950)
__device__ __forceinline__ u32 pack4_fp8(float a, float b, float c, float d) {
  u32 p = __builtin_amdgcn_cvt_pk_fp8_f32(a, b, 0, false);
  p = __builtin_amdgcn_cvt_pk_fp8_f32(c, d, p, true);
  return p;
}
__device__ __forceinline__ u8 f2fp8(float a) {
  return (u8)(__builtin_amdgcn_cvt_pk_fp8_f32(a, a, 0, false) & 0xFF);
}
__device__ __forceinline__ f32x2 unpk_lo(u32 v) {
  return __builtin_amdgcn_cvt_pk_f32_fp8(v, false);
}
__device__ __forceinline__ f32x2 unpk_hi(u32 v) {
  return __builtin_amdgcn_cvt_pk_f32_fp8(v, true);
}

#define GLD16(ldsptr, gptr)                                                     \
  __builtin_amdgcn_global_load_lds(                                             \
      (__attribute__((address_space(1))) void*)(gptr),                          \
      (__attribute__((address_space(3))) void*)(ldsptr), 16, 0, 0)

// ---------------------------------------------------------------------------
// fp32 -> fp8 with scale (A, W1, W2)
// ---------------------------------------------------------------------------
__global__ void convert_f32_fp8(const float* __restrict__ in,
                                u8* __restrict__ out, int n4, float scale) {
  int i = blockIdx.x * blockDim.x + threadIdx.x;
  if (i < n4) {
    float4 v = ((const float4*)in)[i];
    ((u32*)out)[i] =
        pack4_fp8(v.x * scale, v.y * scale, v.z * scale, v.w * scale);
  }
}

// ---------------------------------------------------------------------------
// block reduce helpers (blockDim.x == 256)
// ---------------------------------------------------------------------------
__device__ __forceinline__ float block_reduce1(float v) {
  __shared__ float buf[4];
  for (int o = 32; o; o >>= 1) v += __shfl_down(v, o, 64);
  int lane = threadIdx.x & 63, w = threadIdx.x >> 6;
  if (lane == 0) buf[w] = v;
  __syncthreads();
  float r = 0.f;
  if (threadIdx.x == 0) r = buf[0] + buf[1] + buf[2] + buf[3];
  return r;  // valid on thread 0
}

__device__ __forceinline__ void block_reduce3(float& a, float& b, float& c) {
  __shared__ float buf[3][4];
  for (int o = 32; o; o >>= 1) {
    a += __shfl_down(a, o, 64);
    b += __shfl_down(b, o, 64);
    c += __shfl_down(c, o, 64);
  }
  int lane = threadIdx.x & 63, w = threadIdx.x >> 6;
  if (lane == 0) { buf[0][w] = a; buf[1][w] = b; buf[2][w] = c; }
  __syncthreads();
  if (threadIdx.x == 0) {
    a = buf[0][0] + buf[0][1] + buf[0][2] + buf[0][3];
    b = buf[1][0] + buf[1][1] + buf[1][2] + buf[1][3];
    c = buf[2][0] + buf[2][1] + buf[2][2] + buf[2][3];
  }
}

// ---------------------------------------------------------------------------
// loss_r piece (exact fp32): atomicAdd(out, ||row|| * scale), 1 block/row
// ---------------------------------------------------------------------------
__global__ void rownorm_scaled(const float* __restrict__ M, int cols,
                               float scale, float* __restrict__ out) {
  const float4* row = (const float4*)(M + (size_t)blockIdx.x * cols);
  float s = 0.f;
  for (int i = threadIdx.x; i < cols / 4; i += blockDim.x) {
    float4 v = row[i];
    s += v.x * v.x + v.y * v.y + v.z * v.z + v.w * v.w;
  }
  s = block_reduce1(s);
  if (threadIdx.x == 0) atomicAdd(out, sqrtf(s) * scale);
}

// ---------------------------------------------------------------------------
// MX-scaled fp8 GEMM: C = fp8( WSCALE * sigmoid( invScale*(A B^T) + bias ) )
// A[M][K], B[Nd][K] e4m3 row-major, K % 128 == 0.
// 128x128 tile, BKB=128 fp8 per K-iter, 4 waves 2x2, each 64x64 as 4x4 MFMA
// 16x16x128 f8f6f4 tiles (scale = 1.0 = e8m0 0x7F). Fragment = 32 B/lane:
// global 16-B units 2q, 2q+1 fetched via XOR-swizzled slots (unit ^ (row&7)),
// two ds_read_b128 per fragment handle the swapped-pair case exactly.
// ---------------------------------------------------------------------------
#define BM 128
#define BN 128
#define BKB 128

__global__ __launch_bounds__(256) void gemm_fp8_sigmoid(
    const u8* __restrict__ Ag,    // [M][K]
    const u8* __restrict__ Bg,    // [Nd][K]
    const float* __restrict__ bias,
    u8* __restrict__ Cg,          // [M][Nd] e4m3, value*WSCALE
    float invScale, int K, int Nd) {
  __shared__ __align__(16) u8 Xs[BM * BKB];
  __shared__ __align__(16) u8 Ws[BN * BKB];

  const int tid = threadIdx.x;
  const int wave = tid >> 6, lane = tid & 63;
  const int wr = wave >> 1, wc = wave & 1;
  const size_t rowBase = (size_t)blockIdx.y * BM;
  const size_t colBase = (size_t)blockIdx.x * BN;

  f32x4 acc[4][4] = {};

  const int i8 = lane >> 3;  // row within 8-row staging group
  const int c8 = lane & 7;   // LDS 16-B slot
  const int sw = c8 ^ i8;    // swizzled global 16-B unit

  const int quad = lane >> 4;
  const int m15 = lane & 15;

  for (int k0 = 0; k0 < K; k0 += BKB) {
#pragma unroll
    for (int j = 0; j < 4; ++j) {
      const int r0 = (wave * 4 + j) * 8;
      const u8* gx = Ag + (rowBase + r0 + i8) * (size_t)K + (k0 + sw * 16);
      GLD16(&Xs[r0 * BKB], gx);
      const u8* gw = Bg + (colBase + r0 + i8) * (size_t)K + (k0 + sw * 16);
      GLD16(&Ws[r0 * BKB], gw);
    }
    __syncthreads();

    i32x8 af[4], bfr[4];
#pragma unroll
    for (int t = 0; t < 4; ++t) {
      const int m = wr * 64 + t * 16 + m15;
      i32x4 alo = *(const i32x4*)&Xs[m * BKB + ((2 * quad) ^ (m & 7)) * 16];
      i32x4 ahi = *(const i32x4*)&Xs[m * BKB + ((2 * quad + 1) ^ (m & 7)) * 16];
      af[t] = __builtin_shufflevector(alo, ahi, 0, 1, 2, 3, 4, 5, 6, 7);
      const int n = wc * 64 + t * 16 + m15;
      i32x4 blo = *(const i32x4*)&Ws[n * BKB + ((2 * quad) ^ (n & 7)) * 16];
      i32x4 bhi = *(const i32x4*)&Ws[n * BKB + ((2 * quad + 1) ^ (n & 7)) * 16];
      bfr[t] = __builtin_shufflevector(blo, bhi, 0, 1, 2, 3, 4, 5, 6, 7);
    }
#pragma unroll
    for (int mt = 0; mt < 4; ++mt)
#pragma unroll
      for (int nt = 0; nt < 4; ++nt)
        acc[mt][nt] = __builtin_amdgcn_mfma_scale_f32_16x16x128_f8f6f4(
            af[mt], bfr[nt], acc[mt][nt], 0, 0,
            0, 0x7F7F7F7F, 0, 0x7F7F7F7F);  // fp8/fp8, scales = 1.0
    __syncthreads();
  }

  // epilogue: scale + bias + sigmoid, store fp8 (value * WSCALE)
  float bv[4];
#pragma unroll
  for (int nt = 0; nt < 4; ++nt)
    bv[nt] = bias[colBase + wc * 64 + nt * 16 + m15];
#pragma unroll
  for (int mt = 0; mt < 4; ++mt) {
#pragma unroll
    for (int i = 0; i < 4; ++i) {
      const size_t grow = rowBase + wr * 64 + mt * 16 + quad * 4 + i;
      u8* crow = Cg + grow * (size_t)Nd + colBase + wc * 64 + m15;
#pragma unroll
      for (int nt = 0; nt < 4; ++nt) {
        float x = acc[mt][nt][i] * invScale + bv[nt];
        float s = 1.0f / (1.0f + __expf(-x));
        crow[nt * 16] = f2fp8(s * WSCALE);
      }
    }
  }
}

// ---------------------------------------------------------------------------
// loss_1 layer-1: per edge, ||H1[ni]-H1[nj]|| * lab ; H1 is e4m3 *WSCALE,
// per-node (8192 rows) — gather via edge indices.
// ---------------------------------------------------------------------------
__global__ void edge_loss_h(const u8* __restrict__ H1,
                            const int* __restrict__ edges,
                            const int* __restrict__ labels,
                            float* __restrict__ out) {
  int e = blockIdx.x;
  int ni = edges[e * 2], nj = edges[e * 2 + 1];
  const u32* hi = (const u32*)(H1 + (size_t)ni * H_DIM);
  const u32* hj = (const u32*)(H1 + (size_t)nj * H_DIM);
  float s = 0.f;
  for (int i = threadIdx.x; i < H_DIM / 4; i += blockDim.x) {
    u32 a = hi[i], b = hj[i];
    f32x2 al = unpk_lo(a), ah = unpk_hi(a);
    f32x2 bl = unpk_lo(b), bh = unpk_hi(b);
    float d0 = al.x - bl.x, d1 = al.y - bl.y;
    float d2 = ah.x - bh.x, d3 = ah.y - bh.y;
    s += d0 * d0 + d1 * d1 + d2 * d2 + d3 * d3;
  }
  s = block_reduce1(s);
  if (threadIdx.x == 0 && labels[e] != 0)
    atomicAdd(out, sqrtf(s) * INV_WSCALE);
}

// ---------------------------------------------------------------------------
// loss_1 layer-2 + loss_2; per-node H2 (e4m3 *WSCALE) and A8 (e4m3, x1),
// gathered via edge indices:
//   lab*||Hi2-Hj2|| + factor*(||Xi-Hi2|| + ||Xj-Hj2||)
// ---------------------------------------------------------------------------
__global__ void edge_loss_final(const u8* __restrict__ H2,
                                const u8* __restrict__ A8,
                                const int* __restrict__ edges,
                                const int* __restrict__ labels,
                                float* __restrict__ out) {
  int e = blockIdx.x;
  int ni = edges[e * 2], nj = edges[e * 2 + 1];
  const u32* hi = (const u32*)(H2 + (size_t)ni * N_DIM);
  const u32* hj = (const u32*)(H2 + (size_t)nj * N_DIM);
  const u32* xi = (const u32*)(A8 + (size_t)ni * N_DIM);
  const u32* xj = (const u32*)(A8 + (size_t)nj * N_DIM);
  float s12 = 0.f, si = 0.f, sj = 0.f;
  for (int i = threadIdx.x; i < N_DIM / 4; i += blockDim.x) {
    u32 a = hi[i], b = hj[i], x = xi[i], y = xj[i];
    f32x2 al = unpk_lo(a), ah = unpk_hi(a);
    f32x2 bl = unpk_lo(b), bh = unpk_hi(b);
    f32x2 xl = unpk_lo(x), xh = unpk_hi(x);
    f32x2 yl = unpk_lo(y), yh = unpk_hi(y);
    float ha0 = al.x, ha1 = al.y, ha2 = ah.x, ha3 = ah.y;  // 16*Hi
    float hb0 = bl.x, hb1 = bl.y, hb2 = bh.x, hb3 = bh.y;  // 16*Hj
    float d;
    d = ha0 - hb0; s12 += d * d; d = ha1 - hb1; s12 += d * d;
    d = ha2 - hb2; s12 += d * d; d = ha3 - hb3; s12 += d * d;
    d = WSCALE * xl.x - ha0; si += d * d;
    d = WSCALE * xl.y - ha1; si += d * d;
    d = WSCALE * xh.x - ha2; si += d * d;
    d = WSCALE * xh.y - ha3; si += d * d;
    d = WSCALE * yl.x - hb0; sj += d * d;
    d = WSCALE * yl.y - hb1; sj += d * d;
    d = WSCALE * yh.x - hb2; sj += d * d;
    d = WSCALE * yh.y - hb3; sj += d * d;
  }
  block_reduce3(s12, si, sj);
  if (threadIdx.x == 0) {
    float lab = (labels[e] != 0) ? 1.f : 0.f;
    float fac = (labels[e] != 0) ? PENALTY_F : 1.f;
    atomicAdd(out, (lab * sqrtf(s12) + fac * (sqrtf(si) + sqrtf(sj))) *
                       INV_WSCALE);
  }
}

// ---------------------------------------------------------------------------
extern "C" void kernel_launch(void* const* d_in, const int* in_sizes, int n_in,
                              void* d_out, int out_size, void* d_ws,
                              size_t ws_size, hipStream_t stream) {
  const float* A = (const float*)d_in[0];
  const float* W1 = (const float*)d_in[1];
  const float* b1 = (const float*)d_in[2];
  const float* W2 = (const float*)d_in[3];
  const float* b2 = (const float*)d_in[4];
  const int* edges = (const int*)d_in[5];
  const int* labels = (const int*)d_in[6];
  float* out = (float*)d_out;

  // workspace layout (bytes), total ~152 MB
  char* ws = (char*)d_ws;
  u8* A8   = (u8*)(ws);                       // N x N fp8     64 MB
  u8* H1_8 = (u8*)(ws + 67108864ull);         // N x H fp8      8 MB
  u8* H2_8 = (u8*)(ws + 75497472ull);         // N x N fp8     64 MB
  u8* W1_8 = (u8*)(ws + 142606336ull);        // H x N fp8      8 MB
  u8* W2_8 = (u8*)(ws + 150994944ull);        // N x H fp8      8 MB

  hipMemsetAsync(out, 0, sizeof(float), stream);

  // casts (per-node compute: NO edge gather — dedup halves GEMM FLOPs)
  convert_f32_fp8<<<(N_DIM * N_DIM / 4 + 255) / 256, 256, 0, stream>>>(
      A, A8, N_DIM * N_DIM / 4, 1.0f);
  convert_f32_fp8<<<(H_DIM * N_DIM / 4 + 255) / 256, 256, 0, stream>>>(
      W1, W1_8, H_DIM * N_DIM / 4, WSCALE);
  convert_f32_fp8<<<(N_DIM * H_DIM / 4 + 255) / 256, 256, 0, stream>>>(
      W2, W2_8, N_DIM * H_DIM / 4, WSCALE);

  // loss_r exact in fp32
  rownorm_scaled<<<H_DIM, 256, 0, stream>>>(W1, N_DIM, (float)E_DIM, out);
  rownorm_scaled<<<N_DIM, 256, 0, stream>>>(W2, H_DIM, (float)E_DIM, out);
  rownorm_scaled<<<1, 256, 0, stream>>>(b1, H_DIM, (float)E_DIM, out);
  rownorm_scaled<<<1, 256, 0, stream>>>(b2, N_DIM, (float)E_DIM, out);

  // layer 1 (per node): H1 = sigmoid(A @ W1^T + b1)   [N x H]
  gemm_fp8_sigmoid<<<dim3(H_DIM / BN, N_DIM / BM), 256, 0, stream>>>(
      A8, W1_8, b1, H1_8, INV_WSCALE, N_DIM, H_DIM);
  edge_loss_h<<<E_DIM, 256, 0, stream>>>(H1_8, edges, labels, out);

  // layer 2 (per node): H2 = sigmoid(H1 @ W2^T + b2)  [N x N]
  gemm_fp8_sigmoid<<<dim3(N_DIM / BN, N_DIM / BM), 256, 0, stream>>>(
      H1_8, W2_8, b2, H2_8, INV_WSCALE * INV_WSCALE, H_DIM, N_DIM);
  edge_loss_final<<<E_DIM, 256, 0, stream>>>(H2_8, A8, edges, labels, out);
}